// Round 2
// baseline (122.656 us; speedup 1.0000x reference)
//
#include <hip/hip_runtime.h>
#include <cstddef>

constexpr int NGF    = 80;
constexpr int TLEN   = 1000;
constexpr int SPLICE = 10;
constexpr int PATCH  = 2 * SPLICE + 1;  // 21
constexpr int NH     = 50;
constexpr int BT     = 256;             // t per block

__device__ __forceinline__ float fast_sigmoid(float a) {
    // 1/(1+exp(-a)) = 1/(1+2^(-a*log2(e)))  -> v_mul + v_exp_f32 + v_add + v_rcp_f32
    float e = __builtin_amdgcn_exp2f(a * -1.44269504088896341f);
    return __builtin_amdgcn_rcpf(1.0f + e);
}

__global__ __launch_bounds__(BT) void relevance_fwd(
    const float* __restrict__ x,    // [B, NGF, TLEN]
    const float* __restrict__ W1,   // [NH, PATCH]
    const float* __restrict__ b1,   // [NH]
    const float* __restrict__ W2,   // [NH]  (shape [1,NH])
    const float* __restrict__ b2,   // [1]
    float* __restrict__ out)        // [B, TLEN, NGF]
{
    const int tid = threadIdx.x;
    const int t0  = blockIdx.x * BT;
    const int f   = blockIdx.y;
    const int b   = blockIdx.z;

    __shared__ float s[BT + 2 * SPLICE];  // x segment covering [t0-10, t0+BT+10)

    const float* xrow = x + ((size_t)b * NGF + f) * TLEN;

    int g = t0 - SPLICE + tid;
    s[tid] = (g >= 0 && g < TLEN) ? xrow[g] : 0.0f;
    if (tid < 2 * SPLICE) {
        int g2 = g + BT;
        s[BT + tid] = (g2 >= 0 && g2 < TLEN) ? xrow[g2] : 0.0f;
    }
    __syncthreads();

    const int t = t0 + tid;
    if (t >= TLEN) return;

    // 50 accumulators in VGPRs (all indices static after full unroll).
    float acc[NH];
    #pragma unroll
    for (int j = 0; j < NH; ++j) acc[j] = b1[j];

    // k outer: ONE LDS read feeds 50 FMAs (was 1050 LDS reads/elem in R1).
    #pragma unroll
    for (int k = 0; k < PATCH; ++k) {
        const float pk = s[tid + k];
        #pragma unroll
        for (int j = 0; j < NH; ++j)
            acc[j] = fmaf(W1[j * PATCH + k], pk, acc[j]);  // W1 uniform -> s_load
    }

    float z = b2[0];
    #pragma unroll
    for (int j = 0; j < NH; ++j)
        z = fmaf(W2[j], fast_sigmoid(acc[j]), z);

    out[((size_t)b * TLEN + t) * NGF + f] = fast_sigmoid(z);
}

extern "C" void kernel_launch(void* const* d_in, const int* in_sizes, int n_in,
                              void* d_out, int out_size, void* d_ws, size_t ws_size,
                              hipStream_t stream) {
    const float* x  = (const float*)d_in[0];
    const float* W1 = (const float*)d_in[1];
    const float* b1 = (const float*)d_in[2];
    const float* W2 = (const float*)d_in[3];
    const float* b2 = (const float*)d_in[4];
    float* out = (float*)d_out;

    const int B = in_sizes[0] / (NGF * TLEN);  // 32

    dim3 grid((TLEN + BT - 1) / BT, NGF, B);   // (4, 80, 32)
    relevance_fwd<<<grid, BT, 0, stream>>>(x, W1, b1, W2, b2, out);
}

// Round 3
// 103.728 us; speedup vs baseline: 1.1825x; 1.1825x over previous
//
#include <hip/hip_runtime.h>
#include <cstddef>

constexpr int NGF    = 80;
constexpr int TLEN   = 1000;
constexpr int SPLICE = 10;
constexpr int PATCH  = 2 * SPLICE + 1;  // 21
constexpr int NH     = 50;
constexpr int BT     = 256;             // t per block

__device__ __forceinline__ float fast_sigmoid(float a) {
    // 1/(1+2^(-a*log2e)) -> v_mul + v_exp_f32 + v_add + v_rcp_f32
    float e = __builtin_amdgcn_exp2f(a * -1.44269504088896341f);
    return __builtin_amdgcn_rcpf(1.0f + e);
}

__global__ __launch_bounds__(BT) void relevance_fwd(
    const float* __restrict__ x,    // [B, NGF, TLEN]
    const float* __restrict__ W1,   // [NH, PATCH]
    const float* __restrict__ b1,   // [NH]
    const float* __restrict__ W2,   // [NH]
    const float* __restrict__ b2,   // [1]
    float* __restrict__ out)        // [B, TLEN, NGF]
{
    const int tid = threadIdx.x;
    const int t0  = blockIdx.x * BT;
    const int f   = blockIdx.y;
    const int b   = blockIdx.z;

    __shared__ float s[BT + 2 * SPLICE];

    const float* xrow = x + ((size_t)b * NGF + f) * TLEN;

    int g = t0 - SPLICE + tid;
    s[tid] = (g >= 0 && g < TLEN) ? xrow[g] : 0.0f;
    if (tid < 2 * SPLICE) {
        int g2 = g + BT;
        s[BT + tid] = (g2 >= 0 && g2 < TLEN) ? xrow[g2] : 0.0f;
    }
    __syncthreads();

    const int t = t0 + tid;
    if (t >= TLEN) return;

    // Patch -> registers, then PIN: empty asm makes each value opaque so the
    // compiler cannot rematerialize the LDS load at every use site (the R1/R2
    // failure: 1050 ds_read_b32/elem instead of 21).
    float p[PATCH];
    #pragma unroll
    for (int k = 0; k < PATCH; ++k) p[k] = s[tid + k];
    #pragma unroll
    for (int k = 0; k < PATCH; ++k) asm volatile("" : "+v"(p[k]));

    float z = b2[0];
    #pragma unroll
    for (int j = 0; j < NH; ++j) {
        // two FMA chains to halve dependent-latency (fmaf isn't reassociable)
        float a0 = b1[j];
        float a1 = 0.0f;
        #pragma unroll
        for (int k = 0; k + 1 < PATCH; k += 2) {
            a0 = fmaf(W1[j * PATCH + k],     p[k],     a0);  // W1 uniform -> s_load
            a1 = fmaf(W1[j * PATCH + k + 1], p[k + 1], a1);
        }
        a0 = fmaf(W1[j * PATCH + PATCH - 1], p[PATCH - 1], a0);
        z = fmaf(W2[j], fast_sigmoid(a0 + a1), z);
    }
    out[((size_t)b * TLEN + t) * NGF + f] = fast_sigmoid(z);
}

extern "C" void kernel_launch(void* const* d_in, const int* in_sizes, int n_in,
                              void* d_out, int out_size, void* d_ws, size_t ws_size,
                              hipStream_t stream) {
    const float* x  = (const float*)d_in[0];
    const float* W1 = (const float*)d_in[1];
    const float* b1 = (const float*)d_in[2];
    const float* W2 = (const float*)d_in[3];
    const float* b2 = (const float*)d_in[4];
    float* out = (float*)d_out;

    const int B = in_sizes[0] / (NGF * TLEN);  // 32

    dim3 grid((TLEN + BT - 1) / BT, NGF, B);   // (4, 80, 32)
    relevance_fwd<<<grid, BT, 0, stream>>>(x, W1, b1, W2, b2, out);
}

// Round 4
// 66.586 us; speedup vs baseline: 1.8421x; 1.5578x over previous
//
#include <hip/hip_runtime.h>
#include <cstddef>

constexpr int NGF    = 80;
constexpr int TLEN   = 1000;
constexpr int SPLICE = 10;
constexpr int PATCH  = 2 * SPLICE + 1;  // 21
constexpr int NH     = 50;
constexpr int NTILE  = 63;              // ceil(1000/16)
constexpr int SEGLEN = 1040;            // covers seg idx up to 992+15+31, padded

typedef __attribute__((ext_vector_type(8))) short  short8;
typedef __attribute__((ext_vector_type(4))) float  f32x4;

__device__ __forceinline__ float fast_sigmoid(float a) {
    float e = __builtin_amdgcn_exp2f(a * -1.44269504088896341f);
    return __builtin_amdgcn_rcpf(1.0f + e);
}

__device__ __forceinline__ unsigned short f32_to_bf16(float f) {
    unsigned int u = __builtin_bit_cast(unsigned int, f);
    u += 0x7fffu + ((u >> 16) & 1u);   // RNE
    return (unsigned short)(u >> 16);
}

__global__ __launch_bounds__(256) void relevance_mfma(
    const float* __restrict__ x,    // [B, NGF, TLEN]
    const float* __restrict__ W1,   // [NH, PATCH]
    const float* __restrict__ b1,   // [NH]
    const float* __restrict__ W2,   // [NH]
    const float* __restrict__ b2,   // [1]
    float* __restrict__ out)        // [B, TLEN, NGF]
{
    const int tid  = threadIdx.x;
    const int wave = tid >> 6;
    const int lane = tid & 63;
    const int q    = lane >> 4;     // 16-lane group
    const int jj   = lane & 15;
    const int f    = blockIdx.x % NGF;
    const int b    = blockIdx.x / NGF;

    __shared__ float seg[SEGLEN];   // seg[i] = xpad[i] = x[i-10], zero outside
    const float* xrow = x + ((size_t)b * NGF + f) * TLEN;
    for (int i = tid; i < SEGLEN; i += 256)
        seg[i] = (i >= SPLICE && i < TLEN + SPLICE) ? xrow[i - SPLICE] : 0.0f;
    __syncthreads();

    // ---- B fragments: W1^T [k=21pad32, j=50pad64], k-slot labeling k=8q+e
    // (same labeling used for A below; consistent permutation cancels).
    union FragU { unsigned short us[8]; short8 s8; };
    FragU bf0, bf1, bf2, bf3;
    float b1v[4], w2v[4];
    #pragma unroll
    for (int n = 0; n < 4; ++n) {
        const int j = jj + 16 * n;
        FragU* dst = n == 0 ? &bf0 : n == 1 ? &bf1 : n == 2 ? &bf2 : &bf3;
        #pragma unroll
        for (int e = 0; e < 8; ++e) {
            const int k = 8 * q + e;
            const float w = (j < NH && k < PATCH) ? W1[j * PATCH + k] : 0.0f;
            dst->us[e] = f32_to_bf16(w);
        }
        b1v[n] = (j < NH) ? b1[j] : 0.0f;
        w2v[n] = (j < NH) ? W2[j] : 0.0f;
    }
    const float b2v = b2[0];

    // ---- main loop: each wave owns tiles wave, wave+4, ...
    for (int tile = wave; tile < NTILE; tile += 4) {
        const int t0 = tile * 16;
        const float* sp = &seg[t0 + jj + 8 * q];  // A[r=jj, k=8q+e] = seg[t0+r+k]
        float p0 = sp[0], p1 = sp[1], p2 = sp[2], p3 = sp[3];
        float p4 = sp[4], p5 = sp[5], p6 = sp[6], p7 = sp[7];

        int a0, a1, a2, a3;  // packed bf16 pairs (RNE via HW cvt)
        asm("v_cvt_pk_bf16_f32 %0, %1, %2" : "=v"(a0) : "v"(p0), "v"(p1));
        asm("v_cvt_pk_bf16_f32 %0, %1, %2" : "=v"(a1) : "v"(p2), "v"(p3));
        asm("v_cvt_pk_bf16_f32 %0, %1, %2" : "=v"(a2) : "v"(p4), "v"(p5));
        asm("v_cvt_pk_bf16_f32 %0, %1, %2" : "=v"(a3) : "v"(p6), "v"(p7));
        union { int i[4]; short8 s8; } af;
        af.i[0] = a0; af.i[1] = a1; af.i[2] = a2; af.i[3] = a3;

        f32x4 acc0 = {0,0,0,0}, acc1 = {0,0,0,0}, acc2 = {0,0,0,0}, acc3 = {0,0,0,0};
        acc0 = __builtin_amdgcn_mfma_f32_16x16x32_bf16(af.s8, bf0.s8, acc0, 0, 0, 0);
        acc1 = __builtin_amdgcn_mfma_f32_16x16x32_bf16(af.s8, bf1.s8, acc1, 0, 0, 0);
        acc2 = __builtin_amdgcn_mfma_f32_16x16x32_bf16(af.s8, bf2.s8, acc2, 0, 0, 0);
        acc3 = __builtin_amdgcn_mfma_f32_16x16x32_bf16(af.s8, bf3.s8, acc3, 0, 0, 0);

        // epilogue: h = sigmoid(S + b1), z = sum_j W2[j] h[j]
        // D layout: col(j-part) = jj, row(t-part) = 4q + r
        float z0 = 0.f, z1 = 0.f, z2 = 0.f, z3 = 0.f;
        #pragma unroll
        for (int n = 0; n < 4; ++n) {
            const f32x4 acc = n == 0 ? acc0 : n == 1 ? acc1 : n == 2 ? acc2 : acc3;
            const float bb = b1v[n], ww = w2v[n];
            z0 = fmaf(ww, fast_sigmoid(acc[0] + bb), z0);
            z1 = fmaf(ww, fast_sigmoid(acc[1] + bb), z1);
            z2 = fmaf(ww, fast_sigmoid(acc[2] + bb), z2);
            z3 = fmaf(ww, fast_sigmoid(acc[3] + bb), z3);
        }
        // reduce over the 16 lanes of this row-group (j dimension)
        #pragma unroll
        for (int m = 1; m < 16; m <<= 1) {
            z0 += __shfl_xor(z0, m, 16);
            z1 += __shfl_xor(z1, m, 16);
            z2 += __shfl_xor(z2, m, 16);
            z3 += __shfl_xor(z3, m, 16);
        }
        if (jj < 4) {
            const int t = t0 + 4 * q + jj;
            if (t < TLEN) {
                const float zt = jj == 0 ? z0 : jj == 1 ? z1 : jj == 2 ? z2 : z3;
                out[((size_t)b * TLEN + t) * NGF + f] = fast_sigmoid(zt + b2v);
            }
        }
    }
}

extern "C" void kernel_launch(void* const* d_in, const int* in_sizes, int n_in,
                              void* d_out, int out_size, void* d_ws, size_t ws_size,
                              hipStream_t stream) {
    const float* x  = (const float*)d_in[0];
    const float* W1 = (const float*)d_in[1];
    const float* b1 = (const float*)d_in[2];
    const float* W2 = (const float*)d_in[3];
    const float* b2 = (const float*)d_in[4];
    float* out = (float*)d_out;

    const int B = in_sizes[0] / (NGF * TLEN);  // 32

    dim3 grid(B * NGF);                        // 2560 blocks, one (b,f) row each
    relevance_mfma<<<grid, 256, 0, stream>>>(x, W1, b1, W2, b2, out);
}